// Round 8
// baseline (95.943 us; speedup 1.0000x reference)
//
#include <hip/hip_runtime.h>
#include <math.h>

#define BB 2
#define TT 4096
#define CC 64
#define HH 4
#define DH 16
#define NROW (BB*TT)                 // 8192
#define SCALE 0.36067376022224085f   // 0.25 * log2(e)

typedef __fp16 h4 __attribute__((ext_vector_type(4)));
typedef __fp16 h2 __attribute__((ext_vector_type(2)));
typedef float  f4 __attribute__((ext_vector_type(4)));

// ---------------- Kernel A: qkv GEMM, D[o][r] orientation for packed stores ----------------
// 512 blocks x 256 thr: block = 16 rows; wave w -> output tiles w*3..w*3+2 (of 12)
// Q,K: [bh][T][16] f16.  VT chunk-tiled: [bh][chunk:64][d:16][kcol:64] f16
__global__ __launch_bounds__(256) void qkv_kernel(const float* __restrict__ x,
        const float* __restrict__ w, const float* __restrict__ bias,
        __fp16* __restrict__ Q, __fp16* __restrict__ K, __fp16* __restrict__ VT) {
    __shared__ __fp16 smv[64][16];   // [h*16+d][t-col] staging for V transpose
    const int t = threadIdx.x;
    const int wave = t >> 6, lane = t & 63;
    const int lq = lane & 15, g = lane >> 4;
    const int r0 = blockIdx.x*16;
    const int b = r0 >> 12, tt0 = r0 & (TT-1);

    // B-frag (x^T): lane holds x[r0+lq][s*16 + g*4 + j]
    h4 xb[4];
    const float* xrow = x + (size_t)(r0 + lq)*CC;
    #pragma unroll
    for (int s = 0; s < 4; s++) {
        float4 xv = *(const float4*)(xrow + s*16 + g*4);
        h2 lo = __builtin_amdgcn_cvt_pkrtz(xv.x, xv.y);
        h2 hi = __builtin_amdgcn_cvt_pkrtz(xv.z, xv.w);
        xb[s] = (h4){lo.x, lo.y, hi.x, hi.y};
    }

    #pragma unroll
    for (int j = 0; j < 3; j++) {
        const int nt = wave*3 + j;       // tile: o-range [nt*16, nt*16+16)
        const int o0 = nt*16;
        const float sc = (nt < 4) ? SCALE : 1.0f;
        float4 bv = *(const float4*)(bias + o0 + g*4);
        f4 acc = {bv.x*sc, bv.y*sc, bv.z*sc, bv.w*sc};
        #pragma unroll
        for (int s = 0; s < 4; s++) {
            float4 wv = *(const float4*)(w + (size_t)(o0 + lq)*CC + s*16 + g*4);
            h2 lo = __builtin_amdgcn_cvt_pkrtz(wv.x*sc, wv.y*sc);
            h2 hi = __builtin_amdgcn_cvt_pkrtz(wv.z*sc, wv.w*sc);
            h4 af = (h4){lo.x, lo.y, hi.x, hi.y};
            acc = __builtin_amdgcn_mfma_f32_16x16x16f16(af, xb[s], acc, 0, 0, 0);
        }
        h2 plo = __builtin_amdgcn_cvt_pkrtz(acc.x, acc.y);
        h2 phi = __builtin_amdgcn_cvt_pkrtz(acc.z, acc.w);
        h4 pk = (h4){plo.x, plo.y, phi.x, phi.y};
        if (nt < 8) {
            const int part = nt >> 2, h = nt & 3;
            __fp16* dst = (part == 0) ? Q : K;
            *(h4*)(dst + ((size_t)(b*HH + h)*TT + tt0 + lq)*DH + g*4) = pk;
        } else {
            const int h = nt - 8;
            smv[h*16 + g*4 + 0][lq] = pk.x;
            smv[h*16 + g*4 + 1][lq] = pk.y;
            smv[h*16 + g*4 + 2][lq] = pk.z;
            smv[h*16 + g*4 + 3][lq] = pk.w;
        }
    }
    __syncthreads();
    if (t < 64) {                        // row (h,d) -> 16 t-cols = 32B
        const int h = t >> 4, d = t & 15;
        uint4 v0 = *(const uint4*)&smv[t][0];
        uint4 v1 = *(const uint4*)&smv[t][8];
        __fp16* dst = VT + (size_t)(b*HH + h)*TT*DH
                        + (size_t)((tt0 >> 6)*16 + d)*64 + (tt0 & 63);
        *(uint4*)dst = v0;
        *(uint4*)(dst + 8) = v1;
    }
}

// ---------------- Kernel B: flash attention, 64 q-rows/wave, split-K x8 ----------------
// 512 blocks x 512 thr: block = (head, 64-row qtile); wave w = k-range [w*512,(w+1)*512)
__global__ __launch_bounds__(512) void attn_kernel(const __fp16* __restrict__ Q,
        const __fp16* __restrict__ K, const __fp16* __restrict__ VT,
        __fp16* __restrict__ yh) {
    __shared__ f4    Osm[4][4][64];   // [ksplit-pair][qblk][lane]
    __shared__ float Lsm[4][4][64];
    const int t = threadIdx.x;
    const int wave = t >> 6, lane = t & 63;
    const int lq = lane & 15, g = lane >> 4;
    const int head = blockIdx.x >> 6;
    const int qt   = blockIdx.x & 63;
    const int q0 = qt*64;
    const __fp16* Qh = Q  + (size_t)head*TT*DH;
    const __fp16* Kh = K  + (size_t)head*TT*DH;
    const __fp16* Vh = VT + (size_t)head*TT*DH;

    h4 qf[4];
    #pragma unroll
    for (int h = 0; h < 4; h++)
        qf[h] = *(const h4*)(Qh + (size_t)(q0 + h*16 + lq)*DH + g*4);

    f4 O[4];
    float lp[4];
    #pragma unroll
    for (int h = 0; h < 4; h++) { O[h] = (f4){0.f,0.f,0.f,0.f}; lp[h] = 0.f; }

    // wave's k-range: 8 chunks of 64 kcols
    const __fp16* kp = Kh + (size_t)(wave*512 + lq)*DH + g*4;
    const __fp16* vp = Vh + (size_t)(wave*8)*1024 + lq*64 + g*4;

    h4 ka[4], va[4], kb[4], vb[4];
    #pragma unroll
    for (int s = 0; s < 4; s++) {
        ka[s] = *(const h4*)(kp + (size_t)s*16*DH);
        va[s] = *(const h4*)(vp + s*16);
    }

#define ATTN_CHUNK(KF, VF)                                                        \
    {                                                                             \
        const f4 z = {0.f, 0.f, 0.f, 0.f};                                        \
        _Pragma("unroll")                                                         \
        for (int h = 0; h < 4; h++) {                                             \
            f4 S0 = __builtin_amdgcn_mfma_f32_16x16x16f16(KF[0], qf[h], z, 0,0,0);\
            f4 S1 = __builtin_amdgcn_mfma_f32_16x16x16f16(KF[1], qf[h], z, 0,0,0);\
            f4 S2 = __builtin_amdgcn_mfma_f32_16x16x16f16(KF[2], qf[h], z, 0,0,0);\
            f4 S3 = __builtin_amdgcn_mfma_f32_16x16x16f16(KF[3], qf[h], z, 0,0,0);\
            float p0, p1, p2, p3; h2 lo, hi; h4 P; float lacc = 0.f;              \
            p0 = __builtin_amdgcn_exp2f(S0.x); p1 = __builtin_amdgcn_exp2f(S0.y); \
            p2 = __builtin_amdgcn_exp2f(S0.z); p3 = __builtin_amdgcn_exp2f(S0.w); \
            lacc += p0 + p1 + p2 + p3;                                            \
            lo = __builtin_amdgcn_cvt_pkrtz(p0, p1);                              \
            hi = __builtin_amdgcn_cvt_pkrtz(p2, p3);                              \
            P = (h4){lo.x, lo.y, hi.x, hi.y};                                     \
            O[h] = __builtin_amdgcn_mfma_f32_16x16x16f16(VF[0], P, O[h], 0,0,0);  \
            p0 = __builtin_amdgcn_exp2f(S1.x); p1 = __builtin_amdgcn_exp2f(S1.y); \
            p2 = __builtin_amdgcn_exp2f(S1.z); p3 = __builtin_amdgcn_exp2f(S1.w); \
            lacc += p0 + p1 + p2 + p3;                                            \
            lo = __builtin_amdgcn_cvt_pkrtz(p0, p1);                              \
            hi = __builtin_amdgcn_cvt_pkrtz(p2, p3);                              \
            P = (h4){lo.x, lo.y, hi.x, hi.y};                                     \
            O[h] = __builtin_amdgcn_mfma_f32_16x16x16f16(VF[1], P, O[h], 0,0,0);  \
            p0 = __builtin_amdgcn_exp2f(S2.x); p1 = __builtin_amdgcn_exp2f(S2.y); \
            p2 = __builtin_amdgcn_exp2f(S2.z); p3 = __builtin_amdgcn_exp2f(S2.w); \
            lacc += p0 + p1 + p2 + p3;                                            \
            lo = __builtin_amdgcn_cvt_pkrtz(p0, p1);                              \
            hi = __builtin_amdgcn_cvt_pkrtz(p2, p3);                              \
            P = (h4){lo.x, lo.y, hi.x, hi.y};                                     \
            O[h] = __builtin_amdgcn_mfma_f32_16x16x16f16(VF[2], P, O[h], 0,0,0);  \
            p0 = __builtin_amdgcn_exp2f(S3.x); p1 = __builtin_amdgcn_exp2f(S3.y); \
            p2 = __builtin_amdgcn_exp2f(S3.z); p3 = __builtin_amdgcn_exp2f(S3.w); \
            lacc += p0 + p1 + p2 + p3;                                            \
            lo = __builtin_amdgcn_cvt_pkrtz(p0, p1);                              \
            hi = __builtin_amdgcn_cvt_pkrtz(p2, p3);                              \
            P = (h4){lo.x, lo.y, hi.x, hi.y};                                     \
            O[h] = __builtin_amdgcn_mfma_f32_16x16x16f16(VF[3], P, O[h], 0,0,0);  \
            lp[h] += lacc;                                                        \
        }                                                                         \
    }

    for (int step = 0; step < 8; step += 2) {
        {
            const __fp16* kp1 = kp + (size_t)(step + 1)*64*DH;
            const __fp16* vp1 = vp + (size_t)(step + 1)*1024;
            #pragma unroll
            for (int s = 0; s < 4; s++) {
                kb[s] = *(const h4*)(kp1 + (size_t)s*16*DH);
                vb[s] = *(const h4*)(vp1 + s*16);
            }
        }
        ATTN_CHUNK(ka, va)
        {
            const int c2 = (step + 2 < 8) ? step + 2 : 7;
            const __fp16* kp2 = kp + (size_t)c2*64*DH;
            const __fp16* vp2 = vp + (size_t)c2*1024;
            #pragma unroll
            for (int s = 0; s < 4; s++) {
                ka[s] = *(const h4*)(kp2 + (size_t)s*16*DH);
                va[s] = *(const h4*)(vp2 + s*16);
            }
        }
        ATTN_CHUNK(kb, vb)
    }
#undef ATTN_CHUNK

    // stage 1: upper waves dump partials
    if (wave >= 4) {
        #pragma unroll
        for (int h = 0; h < 4; h++) {
            Osm[wave-4][h][lane] = O[h];
            Lsm[wave-4][h][lane] = lp[h];
        }
    }
    __syncthreads();
    // stage 2: lower waves merge partner, write back combined
    if (wave < 4) {
        #pragma unroll
        for (int h = 0; h < 4; h++) {
            O[h] += Osm[wave][h][lane];
            lp[h] += Lsm[wave][h][lane];
        }
    }
    __syncthreads();
    if (wave < 4) {
        #pragma unroll
        for (int h = 0; h < 4; h++) {
            Osm[wave][h][lane] = O[h];
            Lsm[wave][h][lane] = lp[h];
        }
    }
    __syncthreads();
    // stage 3: wave w (<4) finalizes q-block w; lane owns q=q0+w*16+lq, d=g*4..+3
    if (wave < 4) {
        f4 Os = Osm[0][wave][lane];
        Os += Osm[1][wave][lane];
        Os += Osm[2][wave][lane];
        Os += Osm[3][wave][lane];
        float L = 0.f;
        #pragma unroll
        for (int ks = 0; ks < 4; ks++)
            #pragma unroll
            for (int gg = 0; gg < 4; gg++)
                L += Lsm[ks][wave][gg*16 + lq];
        const float rinv = 1.f / L;
        h2 lo = __builtin_amdgcn_cvt_pkrtz(Os.x*rinv, Os.y*rinv);
        h2 hi = __builtin_amdgcn_cvt_pkrtz(Os.z*rinv, Os.w*rinv);
        h4 pk = (h4){lo.x, lo.y, hi.x, hi.y};
        const int b = head >> 2, hh = head & 3;
        *(h4*)(yh + ((size_t)b*TT + q0 + wave*16 + lq)*CC + hh*DH + g*4) = pk;
    }
}

// ---------------- Kernel C: out = y @ w_proj^T + b_proj, D[r][o-quad] for float4 stores ----------------
// 512 blocks x 256 thr: block = 16 rows; wave w -> o-range [w*16, w*16+16)
__global__ __launch_bounds__(256) void proj_kernel(const __fp16* __restrict__ yh,
        const float* __restrict__ w, const float* __restrict__ bias,
        float* __restrict__ out) {
    const int t = threadIdx.x;
    const int wave = t >> 6, lane = t & 63;
    const int lq = lane & 15, g = lane >> 4;
    const int r0 = blockIdx.x*16;
    const int o0 = wave*16;

    // B-frag (y^T): lane holds y[r0+lq][s*16 + g*4 + j]
    h4 yb[4];
    const __fp16* yrow = yh + (size_t)(r0 + lq)*CC;
    #pragma unroll
    for (int s = 0; s < 4; s++) yb[s] = *(const h4*)(yrow + s*16 + g*4);

    float4 bv = *(const float4*)(bias + o0 + g*4);
    f4 acc = {bv.x, bv.y, bv.z, bv.w};
    #pragma unroll
    for (int s = 0; s < 4; s++) {
        // A-frag (w): lane holds w[o0+lq][s*16 + g*4 + j]
        float4 wv = *(const float4*)(w + (size_t)(o0 + lq)*CC + s*16 + g*4);
        h2 lo = __builtin_amdgcn_cvt_pkrtz(wv.x, wv.y);
        h2 hi = __builtin_amdgcn_cvt_pkrtz(wv.z, wv.w);
        h4 af = (h4){lo.x, lo.y, hi.x, hi.y};
        acc = __builtin_amdgcn_mfma_f32_16x16x16f16(af, yb[s], acc, 0, 0, 0);
    }
    // D: lane holds out[r0+lq][o0 + g*4 .. +3] -> coalesced float4
    *(float4*)(out + (size_t)(r0 + lq)*CC + o0 + g*4) = (float4){acc.x, acc.y, acc.z, acc.w};
}

extern "C" void kernel_launch(void* const* d_in, const int* in_sizes, int n_in,
                              void* d_out, int out_size, void* d_ws, size_t ws_size,
                              hipStream_t stream) {
    const float* x      = (const float*)d_in[0];
    const float* w_attn = (const float*)d_in[1];
    const float* b_attn = (const float*)d_in[2];
    const float* w_proj = (const float*)d_in[3];
    const float* b_proj = (const float*)d_in[4];
    float* out = (float*)d_out;

    const size_t headsz = (size_t)BB*HH*TT*DH;
    __fp16* Q   = (__fp16*)d_ws;
    __fp16* K   = Q + headsz;
    __fp16* VT  = K + headsz;
    __fp16* yh  = VT + headsz;

    qkv_kernel<<<NROW/16, 256, 0, stream>>>(x, w_attn, b_attn, Q, K, VT);
    attn_kernel<<<BB*HH*(TT/64), 512, 0, stream>>>(Q, K, VT, yh);
    proj_kernel<<<NROW/16, 256, 0, stream>>>(yh, w_proj, b_proj, out);
}

// Round 9
// 95.048 us; speedup vs baseline: 1.0094x; 1.0094x over previous
//
#include <hip/hip_runtime.h>
#include <math.h>

#define BB 2
#define TT 4096
#define CC 64
#define HH 4
#define DH 16
#define NROW (BB*TT)                 // 8192
#define SCALE 0.36067376022224085f   // 0.25 * log2(e)

typedef __fp16 h4 __attribute__((ext_vector_type(4)));
typedef __fp16 h2 __attribute__((ext_vector_type(2)));
typedef float  f4 __attribute__((ext_vector_type(4)));

// ---------------- Kernel A: qkv GEMM, D[o][r] orientation for packed stores ----------------
// 512 blocks x 256 thr: block = 16 rows; wave w -> output tiles w*3..w*3+2 (of 12)
// Q,K: [bh][T][16] f16.  VT chunk-tiled: [bh][chunk:64][d:16][kcol:64] f16
__global__ __launch_bounds__(256) void qkv_kernel(const float* __restrict__ x,
        const float* __restrict__ w, const float* __restrict__ bias,
        __fp16* __restrict__ Q, __fp16* __restrict__ K, __fp16* __restrict__ VT) {
    __shared__ __fp16 smv[64][16];   // [h*16+d][t-col] staging for V transpose
    const int t = threadIdx.x;
    const int wave = t >> 6, lane = t & 63;
    const int lq = lane & 15, g = lane >> 4;
    const int r0 = blockIdx.x*16;
    const int b = r0 >> 12, tt0 = r0 & (TT-1);

    // B-frag (x^T): lane holds x[r0+lq][s*16 + g*4 + j]
    h4 xb[4];
    const float* xrow = x + (size_t)(r0 + lq)*CC;
    #pragma unroll
    for (int s = 0; s < 4; s++) {
        float4 xv = *(const float4*)(xrow + s*16 + g*4);
        h2 lo = __builtin_amdgcn_cvt_pkrtz(xv.x, xv.y);
        h2 hi = __builtin_amdgcn_cvt_pkrtz(xv.z, xv.w);
        xb[s] = (h4){lo.x, lo.y, hi.x, hi.y};
    }

    #pragma unroll
    for (int j = 0; j < 3; j++) {
        const int nt = wave*3 + j;       // tile: o-range [nt*16, nt*16+16)
        const int o0 = nt*16;
        const float sc = (nt < 4) ? SCALE : 1.0f;
        float4 bv = *(const float4*)(bias + o0 + g*4);
        f4 acc = {bv.x*sc, bv.y*sc, bv.z*sc, bv.w*sc};
        #pragma unroll
        for (int s = 0; s < 4; s++) {
            float4 wv = *(const float4*)(w + (size_t)(o0 + lq)*CC + s*16 + g*4);
            h2 lo = __builtin_amdgcn_cvt_pkrtz(wv.x*sc, wv.y*sc);
            h2 hi = __builtin_amdgcn_cvt_pkrtz(wv.z*sc, wv.w*sc);
            h4 af = (h4){lo.x, lo.y, hi.x, hi.y};
            acc = __builtin_amdgcn_mfma_f32_16x16x16f16(af, xb[s], acc, 0, 0, 0);
        }
        h2 plo = __builtin_amdgcn_cvt_pkrtz(acc.x, acc.y);
        h2 phi = __builtin_amdgcn_cvt_pkrtz(acc.z, acc.w);
        h4 pk = (h4){plo.x, plo.y, phi.x, phi.y};
        if (nt < 8) {
            const int part = nt >> 2, h = nt & 3;
            __fp16* dst = (part == 0) ? Q : K;
            *(h4*)(dst + ((size_t)(b*HH + h)*TT + tt0 + lq)*DH + g*4) = pk;
        } else {
            const int h = nt - 8;
            smv[h*16 + g*4 + 0][lq] = pk.x;
            smv[h*16 + g*4 + 1][lq] = pk.y;
            smv[h*16 + g*4 + 2][lq] = pk.z;
            smv[h*16 + g*4 + 3][lq] = pk.w;
        }
    }
    __syncthreads();
    if (t < 64) {                        // row (h,d) -> 16 t-cols = 32B
        const int h = t >> 4, d = t & 15;
        uint4 v0 = *(const uint4*)&smv[t][0];
        uint4 v1 = *(const uint4*)&smv[t][8];
        __fp16* dst = VT + (size_t)(b*HH + h)*TT*DH
                        + (size_t)((tt0 >> 6)*16 + d)*64 + (tt0 & 63);
        *(uint4*)dst = v0;
        *(uint4*)(dst + 8) = v1;
    }
}

// ---------------- Kernel B: flash attention, 64 q-rows/wave, split-K x4, phase-staggered ----------------
// 512 blocks x 256 thr: block = (head, 64-row qtile); wave w = k-range [w*1024,(w+1)*1024)
// Each (block,wave) walks its 16-chunk ring starting at a different phase to
// decorrelate the K/V address streams across CUs (L2 contention fix).
__global__ __launch_bounds__(256) void attn_kernel(const __fp16* __restrict__ Q,
        const __fp16* __restrict__ K, const __fp16* __restrict__ VT,
        __fp16* __restrict__ yh) {
    __shared__ f4    Osm[4][4][64];   // [ksplit][qblk][lane]
    __shared__ float Lsm[4][4][64];
    const int t = threadIdx.x;
    const int wave = t >> 6, lane = t & 63;
    const int lq = lane & 15, g = lane >> 4;
    const int head = blockIdx.x >> 6;
    const int qt   = blockIdx.x & 63;
    const int q0 = qt*64;
    const __fp16* Qh = Q  + (size_t)head*TT*DH;
    const __fp16* Kh = K  + (size_t)head*TT*DH;
    const __fp16* Vh = VT + (size_t)head*TT*DH;

    h4 qf[4];
    #pragma unroll
    for (int h = 0; h < 4; h++)
        qf[h] = *(const h4*)(Qh + (size_t)(q0 + h*16 + lq)*DH + g*4);

    f4 O[4];
    float lp[4];
    #pragma unroll
    for (int h = 0; h < 4; h++) { O[h] = (f4){0.f,0.f,0.f,0.f}; lp[h] = 0.f; }

    // chunk-indexed base pointers within this wave's k-range
    const __fp16* kbase = Kh + (size_t)(wave*1024 + lq)*DH + g*4;     // + c*64*DH + s*16*DH
    const __fp16* vbase = Vh + (size_t)(wave*16)*1024 + lq*64 + g*4;  // + c*1024 + s*16

    const int start = (blockIdx.x*5 + wave*3) & 15;   // per-(block,wave) phase

    h4 ka[4], va[4], kb[4], vb[4];
    {
        const int c0 = start;
        #pragma unroll
        for (int s = 0; s < 4; s++) {
            ka[s] = *(const h4*)(kbase + (size_t)c0*64*DH + (size_t)s*16*DH);
            va[s] = *(const h4*)(vbase + (size_t)c0*1024 + s*16);
        }
    }

#define ATTN_CHUNK(KF, VF)                                                        \
    {                                                                             \
        const f4 z = {0.f, 0.f, 0.f, 0.f};                                        \
        _Pragma("unroll")                                                         \
        for (int h = 0; h < 4; h++) {                                             \
            f4 S0 = __builtin_amdgcn_mfma_f32_16x16x16f16(KF[0], qf[h], z, 0,0,0);\
            f4 S1 = __builtin_amdgcn_mfma_f32_16x16x16f16(KF[1], qf[h], z, 0,0,0);\
            f4 S2 = __builtin_amdgcn_mfma_f32_16x16x16f16(KF[2], qf[h], z, 0,0,0);\
            f4 S3 = __builtin_amdgcn_mfma_f32_16x16x16f16(KF[3], qf[h], z, 0,0,0);\
            float p0, p1, p2, p3; h2 lo, hi; h4 P; float lacc = 0.f;              \
            p0 = __builtin_amdgcn_exp2f(S0.x); p1 = __builtin_amdgcn_exp2f(S0.y); \
            p2 = __builtin_amdgcn_exp2f(S0.z); p3 = __builtin_amdgcn_exp2f(S0.w); \
            lacc += p0 + p1 + p2 + p3;                                            \
            lo = __builtin_amdgcn_cvt_pkrtz(p0, p1);                              \
            hi = __builtin_amdgcn_cvt_pkrtz(p2, p3);                              \
            P = (h4){lo.x, lo.y, hi.x, hi.y};                                     \
            O[h] = __builtin_amdgcn_mfma_f32_16x16x16f16(VF[0], P, O[h], 0,0,0);  \
            p0 = __builtin_amdgcn_exp2f(S1.x); p1 = __builtin_amdgcn_exp2f(S1.y); \
            p2 = __builtin_amdgcn_exp2f(S1.z); p3 = __builtin_amdgcn_exp2f(S1.w); \
            lacc += p0 + p1 + p2 + p3;                                            \
            lo = __builtin_amdgcn_cvt_pkrtz(p0, p1);                              \
            hi = __builtin_amdgcn_cvt_pkrtz(p2, p3);                              \
            P = (h4){lo.x, lo.y, hi.x, hi.y};                                     \
            O[h] = __builtin_amdgcn_mfma_f32_16x16x16f16(VF[1], P, O[h], 0,0,0);  \
            p0 = __builtin_amdgcn_exp2f(S2.x); p1 = __builtin_amdgcn_exp2f(S2.y); \
            p2 = __builtin_amdgcn_exp2f(S2.z); p3 = __builtin_amdgcn_exp2f(S2.w); \
            lacc += p0 + p1 + p2 + p3;                                            \
            lo = __builtin_amdgcn_cvt_pkrtz(p0, p1);                              \
            hi = __builtin_amdgcn_cvt_pkrtz(p2, p3);                              \
            P = (h4){lo.x, lo.y, hi.x, hi.y};                                     \
            O[h] = __builtin_amdgcn_mfma_f32_16x16x16f16(VF[2], P, O[h], 0,0,0);  \
            p0 = __builtin_amdgcn_exp2f(S3.x); p1 = __builtin_amdgcn_exp2f(S3.y); \
            p2 = __builtin_amdgcn_exp2f(S3.z); p3 = __builtin_amdgcn_exp2f(S3.w); \
            lacc += p0 + p1 + p2 + p3;                                            \
            lo = __builtin_amdgcn_cvt_pkrtz(p0, p1);                              \
            hi = __builtin_amdgcn_cvt_pkrtz(p2, p3);                              \
            P = (h4){lo.x, lo.y, hi.x, hi.y};                                     \
            O[h] = __builtin_amdgcn_mfma_f32_16x16x16f16(VF[3], P, O[h], 0,0,0);  \
            lp[h] += lacc;                                                        \
        }                                                                         \
    }

    for (int it = 0; it < 16; it += 2) {
        {
            const int c1 = (start + it + 1) & 15;
            #pragma unroll
            for (int s = 0; s < 4; s++) {
                kb[s] = *(const h4*)(kbase + (size_t)c1*64*DH + (size_t)s*16*DH);
                vb[s] = *(const h4*)(vbase + (size_t)c1*1024 + s*16);
            }
        }
        ATTN_CHUNK(ka, va)
        {
            const int c2 = (start + it + 2) & 15;   // wraps to start on last iter (redundant load, harmless)
            #pragma unroll
            for (int s = 0; s < 4; s++) {
                ka[s] = *(const h4*)(kbase + (size_t)c2*64*DH + (size_t)s*16*DH);
                va[s] = *(const h4*)(vbase + (size_t)c2*1024 + s*16);
            }
        }
        ATTN_CHUNK(kb, vb)
    }
#undef ATTN_CHUNK

    #pragma unroll
    for (int h = 0; h < 4; h++) {
        Osm[wave][h][lane] = O[h];
        Lsm[wave][h][lane] = lp[h];
    }
    __syncthreads();

    // wave w combines q-block w; lane owns q = q0 + w*16 + lq, d = g*4..g*4+3
    f4 Os = Osm[0][wave][lane];
    Os += Osm[1][wave][lane];
    Os += Osm[2][wave][lane];
    Os += Osm[3][wave][lane];
    float L = 0.f;
    #pragma unroll
    for (int ks = 0; ks < 4; ks++)
        #pragma unroll
        for (int gg = 0; gg < 4; gg++)
            L += Lsm[ks][wave][gg*16 + lq];
    const float rinv = 1.f / L;
    h2 lo = __builtin_amdgcn_cvt_pkrtz(Os.x*rinv, Os.y*rinv);
    h2 hi = __builtin_amdgcn_cvt_pkrtz(Os.z*rinv, Os.w*rinv);
    h4 pk = (h4){lo.x, lo.y, hi.x, hi.y};
    const int b = head >> 2, hh = head & 3;
    *(h4*)(yh + ((size_t)b*TT + q0 + wave*16 + lq)*CC + hh*DH + g*4) = pk;
}

// ---------------- Kernel C: out = y @ w_proj^T + b_proj, D[r][o-quad] for float4 stores ----------------
// 512 blocks x 256 thr: block = 16 rows; wave w -> o-range [w*16, w*16+16)
__global__ __launch_bounds__(256) void proj_kernel(const __fp16* __restrict__ yh,
        const float* __restrict__ w, const float* __restrict__ bias,
        float* __restrict__ out) {
    const int t = threadIdx.x;
    const int wave = t >> 6, lane = t & 63;
    const int lq = lane & 15, g = lane >> 4;
    const int r0 = blockIdx.x*16;
    const int o0 = wave*16;

    // B-frag (y^T): lane holds y[r0+lq][s*16 + g*4 + j]
    h4 yb[4];
    const __fp16* yrow = yh + (size_t)(r0 + lq)*CC;
    #pragma unroll
    for (int s = 0; s < 4; s++) yb[s] = *(const h4*)(yrow + s*16 + g*4);

    float4 bv = *(const float4*)(bias + o0 + g*4);
    f4 acc = {bv.x, bv.y, bv.z, bv.w};
    #pragma unroll
    for (int s = 0; s < 4; s++) {
        // A-frag (w): lane holds w[o0+lq][s*16 + g*4 + j]
        float4 wv = *(const float4*)(w + (size_t)(o0 + lq)*CC + s*16 + g*4);
        h2 lo = __builtin_amdgcn_cvt_pkrtz(wv.x, wv.y);
        h2 hi = __builtin_amdgcn_cvt_pkrtz(wv.z, wv.w);
        h4 af = (h4){lo.x, lo.y, hi.x, hi.y};
        acc = __builtin_amdgcn_mfma_f32_16x16x16f16(af, yb[s], acc, 0, 0, 0);
    }
    // D: lane holds out[r0+lq][o0 + g*4 .. +3] -> coalesced float4
    *(float4*)(out + (size_t)(r0 + lq)*CC + o0 + g*4) = (float4){acc.x, acc.y, acc.z, acc.w};
}

extern "C" void kernel_launch(void* const* d_in, const int* in_sizes, int n_in,
                              void* d_out, int out_size, void* d_ws, size_t ws_size,
                              hipStream_t stream) {
    const float* x      = (const float*)d_in[0];
    const float* w_attn = (const float*)d_in[1];
    const float* b_attn = (const float*)d_in[2];
    const float* w_proj = (const float*)d_in[3];
    const float* b_proj = (const float*)d_in[4];
    float* out = (float*)d_out;

    const size_t headsz = (size_t)BB*HH*TT*DH;
    __fp16* Q   = (__fp16*)d_ws;
    __fp16* K   = Q + headsz;
    __fp16* VT  = K + headsz;
    __fp16* yh  = VT + headsz;

    qkv_kernel<<<NROW/16, 256, 0, stream>>>(x, w_attn, b_attn, Q, K, VT);
    attn_kernel<<<BB*HH*(TT/64), 256, 0, stream>>>(Q, K, VT, yh);
    proj_kernel<<<NROW/16, 256, 0, stream>>>(yh, w_proj, b_proj, out);
}